// Round 7
// baseline (496.756 us; speedup 1.0000x reference)
//
#include <hip/hip_runtime.h>

#define Bsz 16
#define Nn  100000
#define Ee  2000000
#define Dd  512
#define Cc  10
#define NB  (Nn * Bsz)
#define NB4 (NB / 4)                            // 400000 gather threads
#define SCAN_BLK 1024
#define NSB ((Nn + SCAN_BLK - 1) / SCAN_BLK)   // 98
#define NPARTS ((NB4 + 255) / 256)              // 1563 gather blocks

// ---- ordered-uint encoding for float min/max (monotone map) ----
__device__ __forceinline__ unsigned enc_f(float f) {
    unsigned u = __float_as_uint(f);
    return (u & 0x80000000u) ? ~u : (u | 0x80000000u);
}
__device__ __forceinline__ float dec_f(unsigned e) {
    unsigned u = (e & 0x80000000u) ? (e ^ 0x80000000u) : ~e;
    return __uint_as_float(u);
}

// LDS-tiled transpose x (B,N) -> xb[n*16+b] (coalesced both sides);
// thr[n]=|nt[n]|; zero histogram
__global__ void prep(const float* __restrict__ x, const float* __restrict__ nt,
                     float* __restrict__ xb, float* __restrict__ thr,
                     int* __restrict__ cnt) {
    __shared__ float sm[16][65];
    int t = threadIdx.x;
    int n0 = blockIdx.x * 64;
    #pragma unroll
    for (int rep = 0; rep < 4; rep++) {
        int r = rep * 4 + (t >> 6);      // batch row 0..15
        int c = t & 63;                  // node within tile
        int n = n0 + c;
        sm[r][c] = (n < Nn) ? x[r * Nn + n] : 0.0f;
    }
    __syncthreads();
    int nn = t >> 2, bq = t & 3;
    int n = n0 + nn;
    if (n < Nn) {
        float4 v;
        v.x = sm[bq * 4 + 0][nn];
        v.y = sm[bq * 4 + 1][nn];
        v.z = sm[bq * 4 + 2][nn];
        v.w = sm[bq * 4 + 3][nn];
        ((float4*)xb)[n * 4 + bq] = v;
    }
    int gid = blockIdx.x * 256 + t;
    if (gid < Nn) { thr[gid] = fabsf(nt[gid]); cnt[gid] = 0; }
}

__global__ void hist(const int* __restrict__ dstv, int* __restrict__ cnt) {
    int e = blockIdx.x * blockDim.x + threadIdx.x;
    if (e < Ee) atomicAdd(&cnt[dstv[e]], 1);
}

// per-block inclusive scan (Hillis-Steele) + block sums
__global__ void scan1(const int* __restrict__ cnt, int* __restrict__ incl,
                      int* __restrict__ bsum) {
    __shared__ int s[SCAN_BLK];
    int i = blockIdx.x * SCAN_BLK + threadIdx.x;
    int v = (i < Nn) ? cnt[i] : 0;
    s[threadIdx.x] = v;
    __syncthreads();
    for (int off = 1; off < SCAN_BLK; off <<= 1) {
        int t = (threadIdx.x >= off) ? s[threadIdx.x - off] : 0;
        __syncthreads();
        s[threadIdx.x] += t;
        __syncthreads();
    }
    if (i < Nn) incl[i] = s[threadIdx.x];
    if (threadIdx.x == SCAN_BLK - 1) bsum[blockIdx.x] = s[threadIdx.x];
}

__global__ void scan2(const int* __restrict__ bsum, int* __restrict__ bofs) {
    if (threadIdx.x == 0) {
        int acc = 0;
        for (int k = 0; k < NSB; k++) { bofs[k] = acc; acc += bsum[k]; }
    }
}

// exclusive row offsets + scatter cursors
__global__ void scan3(const int* __restrict__ cnt, const int* __restrict__ incl,
                      const int* __restrict__ bofs, int* __restrict__ row,
                      int* __restrict__ cur) {
    int i = blockIdx.x * blockDim.x + threadIdx.x;
    if (i < Nn) {
        int excl = incl[i] - cnt[i] + bofs[i / SCAN_BLK];
        row[i] = excl;
        cur[i] = excl;
    }
    if (i == 0) row[Nn] = Ee;
}

// permute edges into CSR-by-dst. Scattered 8B store is NON-TEMPORAL:
// bypass L2 write-allocate (no fetch-allocate-evict of random 64B lines).
__global__ void build(const int* __restrict__ srcv, const int* __restrict__ dstv,
                      const float* __restrict__ ew, const float* __restrict__ mult,
                      int* __restrict__ cur, int2* __restrict__ csr_sw) {
    int e = blockIdx.x * blockDim.x + threadIdx.x;
    if (e < Ee) {
        int d = dstv[e];
        int pos = atomicAdd(&cur[d], 1);
        int2 p;
        p.x = srcv[e];
        p.y = __float_as_int(ew[e] * tanhf(mult[e]));
        long long pv;
        __builtin_memcpy(&pv, &p, 8);
        __builtin_nontemporal_store(pv, (long long*)&csr_sw[pos]);
    }
}

// thread = (node, b-quad): each thread accumulates a float4 (4 batch slots).
// 4 lanes/node -> one v-load instruction requests 16 distinct 64B lines per
// wave (4x the line-level parallelism of the 16-lane/node layout), and 8-wide
// edge unroll keeps 8 paired CSR loads + 8 float4 loads in flight.
__global__ void gather(const int* __restrict__ row, const int2* __restrict__ csr_sw,
                       const float* __restrict__ xb, float* __restrict__ aggr,
                       uint2* __restrict__ part) {
    int i = blockIdx.x * 256 + threadIdx.x;
    bool active = i < NB4;
    float4 acc = make_float4(0.f, 0.f, 0.f, 0.f);
    if (active) {
        int n = i >> 2, bq = i & 3;
        int ks = row[n], ke = row[n + 1];
        const float4* xb4 = (const float4*)xb;
        for (int k = ks; k < ke; k += 8) {
            int2   p[8];
            float4 v[8];
            #pragma unroll
            for (int j = 0; j < 8; ++j) {
                int kk = k + j;
                int kc = kk < ke ? kk : ks;          // always a valid index
                p[j] = csr_sw[kc];
                if (kk >= ke) p[j].y = 0;            // 0.0f weight for dead slots
            }
            #pragma unroll
            for (int j = 0; j < 8; ++j) v[j] = xb4[p[j].x * 4 + bq];
            #pragma unroll
            for (int j = 0; j < 8; ++j) {
                float w = __int_as_float(p[j].y);
                acc.x += v[j].x * w;
                acc.y += v[j].y * w;
                acc.z += v[j].z * w;
                acc.w += v[j].w * w;
            }
        }
        ((float4*)aggr)[i] = acc;
    }

    float lmin = active ? fminf(fminf(acc.x, acc.y), fminf(acc.z, acc.w)) : INFINITY;
    float lmax = active ? fmaxf(fmaxf(acc.x, acc.y), fmaxf(acc.z, acc.w)) : -INFINITY;
    #pragma unroll
    for (int off = 32; off > 0; off >>= 1) {
        lmin = fminf(lmin, __shfl_down(lmin, off));
        lmax = fmaxf(lmax, __shfl_down(lmax, off));
    }
    __shared__ float smin[4], smax[4];
    int wid = threadIdx.x >> 6, lane = threadIdx.x & 63;
    if (lane == 0) { smin[wid] = lmin; smax[wid] = lmax; }
    __syncthreads();
    if (threadIdx.x == 0) {
        float m0 = smin[0], M0 = smax[0];
        #pragma unroll
        for (int k = 1; k < 4; k++) { m0 = fminf(m0, smin[k]); M0 = fmaxf(M0, smax[k]); }
        part[blockIdx.x] = make_uint2(enc_f(m0), enc_f(M0));   // plain store
    }
}

// fold per-block partials -> mm[0]=min, mm[1]=max. One block, no atomics.
__global__ void mm_reduce(const uint2* __restrict__ part, unsigned* __restrict__ mm) {
    unsigned lmin = 0xFFFFFFFFu, lmax = 0u;
    for (int i = threadIdx.x; i < NPARTS; i += 1024) {
        uint2 p = part[i];
        lmin = min(lmin, p.x);
        lmax = max(lmax, p.y);
    }
    #pragma unroll
    for (int off = 32; off > 0; off >>= 1) {
        lmin = min(lmin, __shfl_down(lmin, off));
        lmax = max(lmax, __shfl_down(lmax, off));
    }
    __shared__ unsigned smn[16], smx[16];
    int wid = threadIdx.x >> 6, lane = threadIdx.x & 63;
    if (lane == 0) { smn[wid] = lmin; smx[wid] = lmax; }
    __syncthreads();
    if (threadIdx.x == 0) {
        #pragma unroll
        for (int k = 1; k < 16; k++) { lmin = min(lmin, smn[k]); lmax = max(lmax, smx[k]); }
        mm[0] = lmin;
        mm[1] = lmax;
    }
}

// float4-vectorized sigmoid update
__global__ void update(const float* __restrict__ aggr, const float* __restrict__ thr,
                       const unsigned* __restrict__ mm, float* __restrict__ xb) {
    int q = blockIdx.x * blockDim.x + threadIdx.x;   // NB/4 quads
    if (q < NB / 4) {
        float amin = dec_f(mm[0]), amax = dec_f(mm[1]);
        float inv = 1.0f / (amax - amin);
        int n = q >> 2;
        float t = thr[n];
        float4 a = ((const float4*)aggr)[q];
        float4 r;
        r.x = 1.0f / (1.0f + expf(-((a.x - amin) * inv - t)));
        r.y = 1.0f / (1.0f + expf(-((a.y - amin) * inv - t)));
        r.z = 1.0f / (1.0f + expf(-((a.z - amin) * inv - t)));
        r.w = 1.0f / (1.0f + expf(-((a.w - amin) * inv - t)));
        ((float4*)xb)[q] = r;
    }
}

// gather decision nodes + (16x512)@(512x10) matmul, single block of 512 threads
__global__ void final_k(const float* __restrict__ xb, const int* __restrict__ dix,
                        const float* __restrict__ fcw, const float* __restrict__ fcb,
                        float* __restrict__ out) {
    __shared__ float xd[Dd][Bsz];   // 32 KB
    int j = threadIdx.x;
    int n = dix[j];
    #pragma unroll
    for (int b = 0; b < Bsz; b++) xd[j][b] = xb[n * 16 + b];
    __syncthreads();
    if (j < Bsz * Cc) {
        int b = j / Cc, c = j % Cc;
        float acc = fcb[c];
        for (int k = 0; k < Dd; k++) acc += xd[k][b] * fcw[c * Dd + k];
        out[b * Cc + c] = acc;
    }
}

extern "C" void kernel_launch(void* const* d_in, const int* in_sizes, int n_in,
                              void* d_out, int out_size, void* d_ws, size_t ws_size,
                              hipStream_t stream) {
    const float* x    = (const float*)d_in[0];
    const float* ew   = (const float*)d_in[1];
    const float* mult = (const float*)d_in[2];
    const float* nt   = (const float*)d_in[3];
    const float* fcw  = (const float*)d_in[4];
    const float* fcb  = (const float*)d_in[5];
    const int*   ei   = (const int*)d_in[6];
    const int*   dix  = (const int*)d_in[7];
    float* out = (float*)d_out;

    const int* srcv = ei;
    const int* dstv = ei + Ee;

    // workspace layout (~31.6 MB)
    float* xb      = (float*)d_ws;              // NB
    float* aggr    = xb + NB;                   // NB
    float* thr     = aggr + NB;                 // Nn
    int2*  csr_sw  = (int2*)(thr + Nn);         // Ee (8B aligned)
    uint2* part    = (uint2*)(csr_sw + Ee);     // NPARTS (8B aligned)
    int*   row     = (int*)(part + NPARTS);     // Nn+1
    int*   cur     = row + Nn + 1;              // Nn
    int*   cnt     = cur + Nn;                  // Nn
    int*   incl    = cnt + Nn;                  // Nn
    int*   bsum    = incl + Nn;                 // NSB
    int*   bofs    = bsum + NSB;                // NSB
    unsigned* mm   = (unsigned*)(bofs + NSB);   // 2

    prep<<<(Nn + 63) / 64, 256, 0, stream>>>(x, nt, xb, thr, cnt);
    hist<<<(Ee + 255) / 256, 256, 0, stream>>>(dstv, cnt);
    scan1<<<NSB, SCAN_BLK, 0, stream>>>(cnt, incl, bsum);
    scan2<<<1, 64, 0, stream>>>(bsum, bofs);
    scan3<<<(Nn + 255) / 256, 256, 0, stream>>>(cnt, incl, bofs, row, cur);
    build<<<(Ee + 255) / 256, 256, 0, stream>>>(srcv, dstv, ew, mult, cur, csr_sw);

    for (int p = 0; p < 4; p++) {
        gather<<<NPARTS, 256, 0, stream>>>(row, csr_sw, xb, aggr, part);
        mm_reduce<<<1, 1024, 0, stream>>>(part, mm);
        update<<<(NB / 4 + 255) / 256, 256, 0, stream>>>(aggr, thr, mm, xb);
    }

    final_k<<<1, 512, 0, stream>>>(xb, dix, fcw, fcb, out);
}

// Round 8
// 475.091 us; speedup vs baseline: 1.0456x; 1.0456x over previous
//
#include <hip/hip_runtime.h>

#define Bsz 16
#define Nn  100000
#define Ee  2000000
#define Dd  512
#define Cc  10
#define NB  (Nn * Bsz)
#define NB4 (NB / 4)                            // 400000 gather threads
#define SCAN_BLK 1024
#define NSB ((Nn + SCAN_BLK - 1) / SCAN_BLK)   // 98
#define NPARTS ((NB4 + 255) / 256)              // 1563 gather blocks
#define NBK ((Nn + 255) / 256)                  // 391 dst buckets (256 nodes each)
#define BPAD 16                                 // bucket cursor padding (1 per 64B line)
#define SEDMAX 7808                             // LDS edge staging cap (62.5 KB)

// ---- ordered-uint encoding for float min/max (monotone map) ----
__device__ __forceinline__ unsigned enc_f(float f) {
    unsigned u = __float_as_uint(f);
    return (u & 0x80000000u) ? ~u : (u | 0x80000000u);
}
__device__ __forceinline__ float dec_f(unsigned e) {
    unsigned u = (e & 0x80000000u) ? (e ^ 0x80000000u) : ~e;
    return __uint_as_float(u);
}

// LDS-tiled transpose x (B,N) -> xb[n*16+b] (coalesced both sides);
// thr[n]=|nt[n]|; zero histogram
__global__ void prep(const float* __restrict__ x, const float* __restrict__ nt,
                     float* __restrict__ xb, float* __restrict__ thr,
                     int* __restrict__ cnt) {
    __shared__ float sm[16][65];
    int t = threadIdx.x;
    int n0 = blockIdx.x * 64;
    #pragma unroll
    for (int rep = 0; rep < 4; rep++) {
        int r = rep * 4 + (t >> 6);      // batch row 0..15
        int c = t & 63;                  // node within tile
        int n = n0 + c;
        sm[r][c] = (n < Nn) ? x[r * Nn + n] : 0.0f;
    }
    __syncthreads();
    int nn = t >> 2, bq = t & 3;
    int n = n0 + nn;
    if (n < Nn) {
        float4 v;
        v.x = sm[bq * 4 + 0][nn];
        v.y = sm[bq * 4 + 1][nn];
        v.z = sm[bq * 4 + 2][nn];
        v.w = sm[bq * 4 + 3][nn];
        ((float4*)xb)[n * 4 + bq] = v;
    }
    int gid = blockIdx.x * 256 + t;
    if (gid < Nn) { thr[gid] = fabsf(nt[gid]); cnt[gid] = 0; }
}

__global__ void hist(const int* __restrict__ dstv, int* __restrict__ cnt) {
    int e = blockIdx.x * blockDim.x + threadIdx.x;
    if (e < Ee) atomicAdd(&cnt[dstv[e]], 1);
}

// per-block inclusive scan (Hillis-Steele) + block sums
__global__ void scan1(const int* __restrict__ cnt, int* __restrict__ incl,
                      int* __restrict__ bsum) {
    __shared__ int s[SCAN_BLK];
    int i = blockIdx.x * SCAN_BLK + threadIdx.x;
    int v = (i < Nn) ? cnt[i] : 0;
    s[threadIdx.x] = v;
    __syncthreads();
    for (int off = 1; off < SCAN_BLK; off <<= 1) {
        int t = (threadIdx.x >= off) ? s[threadIdx.x - off] : 0;
        __syncthreads();
        s[threadIdx.x] += t;
        __syncthreads();
    }
    if (i < Nn) incl[i] = s[threadIdx.x];
    if (threadIdx.x == SCAN_BLK - 1) bsum[blockIdx.x] = s[threadIdx.x];
}

__global__ void scan2(const int* __restrict__ bsum, int* __restrict__ bofs) {
    if (threadIdx.x == 0) {
        int acc = 0;
        for (int k = 0; k < NSB; k++) { bofs[k] = acc; acc += bsum[k]; }
    }
}

// exclusive row offsets
__global__ void scan3(const int* __restrict__ cnt, const int* __restrict__ incl,
                      const int* __restrict__ bofs, int* __restrict__ row) {
    int i = blockIdx.x * blockDim.x + threadIdx.x;
    if (i < Nn) row[i] = incl[i] - cnt[i] + bofs[i / SCAN_BLK];
    if (i == 0) row[Nn] = Ee;
}

// init bucket cursors (one per 64B line to avoid same-line atomic serialization)
__global__ void binit(const int* __restrict__ row, int* __restrict__ bcur) {
    int b = blockIdx.x * blockDim.x + threadIdx.x;
    if (b < NBK) bcur[b * BPAD] = row[b * 256];
}

// level-1: partition edges into 391 dst-buckets. Only ~391 active write
// frontiers (25 KB) -> L2 write-combining works (vs 100K frontiers = 6.4MB
// before, which evicted lines nearly empty -> 8x write amplification).
// Pack: word0 = src | (dst&255)<<17 ; word1 = w = ew*tanh(mult).
__global__ void bin1(const int* __restrict__ srcv, const int* __restrict__ dstv,
                     const float* __restrict__ ew, const float* __restrict__ mult,
                     int* __restrict__ bcur, int2* __restrict__ csr_sw) {
    int e = blockIdx.x * blockDim.x + threadIdx.x;
    if (e < Ee) {
        int d = dstv[e];
        int pos = atomicAdd(&bcur[(d >> 8) * BPAD], 1);
        int2 p;
        p.x = srcv[e] | ((d & 255) << 17);
        p.y = __float_as_int(ew[e] * tanhf(mult[e]));
        csr_sw[pos] = p;
    }
}

// level-2: in-place counting sort within each bucket. Bucket edges staged in
// LDS (<= ~5.5K expected, SEDMAX cap), per-node cursors = LDS atomics, writes
// land in the bucket's contiguous ~40KB CSR window (L2-resident).
__global__ void bin2(const int* __restrict__ row, int2* __restrict__ csr_sw) {
    __shared__ int2 sed[SEDMAX];
    __shared__ int lcur[256];
    int b = blockIdx.x;
    int n0 = b * 256;
    int n1 = min(n0 + 256, Nn);
    int e0 = row[n0], e1 = row[n1];
    int cnt = e1 - e0;
    if (cnt > SEDMAX) cnt = SEDMAX;   // statistically unreachable (+37 sigma)
    for (int t = threadIdx.x; t < cnt; t += 256) sed[t] = csr_sw[e0 + t];
    lcur[threadIdx.x] = (n0 + threadIdx.x < n1) ? row[n0 + threadIdx.x] : 0;
    __syncthreads();
    for (int t = threadIdx.x; t < cnt; t += 256) {
        int2 p = sed[t];
        int nl = (p.x >> 17) & 255;
        int pos = atomicAdd(&lcur[nl], 1);
        int2 q;
        q.x = p.x & 0x1FFFF;
        q.y = p.y;
        csr_sw[pos] = q;
    }
}

// thread = (node, b-quad): each thread accumulates a float4 (4 batch slots).
// 8-wide edge unroll keeps 8 paired CSR loads + 8 float4 loads in flight.
__global__ void gather(const int* __restrict__ row, const int2* __restrict__ csr_sw,
                       const float* __restrict__ xb, float* __restrict__ aggr,
                       uint2* __restrict__ part) {
    int i = blockIdx.x * 256 + threadIdx.x;
    bool active = i < NB4;
    float4 acc = make_float4(0.f, 0.f, 0.f, 0.f);
    if (active) {
        int n = i >> 2, bq = i & 3;
        int ks = row[n], ke = row[n + 1];
        const float4* xb4 = (const float4*)xb;
        for (int k = ks; k < ke; k += 8) {
            int2   p[8];
            float4 v[8];
            #pragma unroll
            for (int j = 0; j < 8; ++j) {
                int kk = k + j;
                int kc = kk < ke ? kk : ks;          // always a valid index
                p[j] = csr_sw[kc];
                if (kk >= ke) p[j].y = 0;            // 0.0f weight for dead slots
            }
            #pragma unroll
            for (int j = 0; j < 8; ++j) v[j] = xb4[p[j].x * 4 + bq];
            #pragma unroll
            for (int j = 0; j < 8; ++j) {
                float w = __int_as_float(p[j].y);
                acc.x += v[j].x * w;
                acc.y += v[j].y * w;
                acc.z += v[j].z * w;
                acc.w += v[j].w * w;
            }
        }
        ((float4*)aggr)[i] = acc;
    }

    float lmin = active ? fminf(fminf(acc.x, acc.y), fminf(acc.z, acc.w)) : INFINITY;
    float lmax = active ? fmaxf(fmaxf(acc.x, acc.y), fmaxf(acc.z, acc.w)) : -INFINITY;
    #pragma unroll
    for (int off = 32; off > 0; off >>= 1) {
        lmin = fminf(lmin, __shfl_down(lmin, off));
        lmax = fmaxf(lmax, __shfl_down(lmax, off));
    }
    __shared__ float smin[4], smax[4];
    int wid = threadIdx.x >> 6, lane = threadIdx.x & 63;
    if (lane == 0) { smin[wid] = lmin; smax[wid] = lmax; }
    __syncthreads();
    if (threadIdx.x == 0) {
        float m0 = smin[0], M0 = smax[0];
        #pragma unroll
        for (int k = 1; k < 4; k++) { m0 = fminf(m0, smin[k]); M0 = fmaxf(M0, smax[k]); }
        part[blockIdx.x] = make_uint2(enc_f(m0), enc_f(M0));   // plain store
    }
}

// fold per-block partials -> mm[0]=min, mm[1]=max. One block, no atomics.
__global__ void mm_reduce(const uint2* __restrict__ part, unsigned* __restrict__ mm) {
    unsigned lmin = 0xFFFFFFFFu, lmax = 0u;
    for (int i = threadIdx.x; i < NPARTS; i += 1024) {
        uint2 p = part[i];
        lmin = min(lmin, p.x);
        lmax = max(lmax, p.y);
    }
    #pragma unroll
    for (int off = 32; off > 0; off >>= 1) {
        lmin = min(lmin, __shfl_down(lmin, off));
        lmax = max(lmax, __shfl_down(lmax, off));
    }
    __shared__ unsigned smn[16], smx[16];
    int wid = threadIdx.x >> 6, lane = threadIdx.x & 63;
    if (lane == 0) { smn[wid] = lmin; smx[wid] = lmax; }
    __syncthreads();
    if (threadIdx.x == 0) {
        #pragma unroll
        for (int k = 1; k < 16; k++) { lmin = min(lmin, smn[k]); lmax = max(lmax, smx[k]); }
        mm[0] = lmin;
        mm[1] = lmax;
    }
}

// float4-vectorized sigmoid update
__global__ void update(const float* __restrict__ aggr, const float* __restrict__ thr,
                       const unsigned* __restrict__ mm, float* __restrict__ xb) {
    int q = blockIdx.x * blockDim.x + threadIdx.x;   // NB/4 quads
    if (q < NB / 4) {
        float amin = dec_f(mm[0]), amax = dec_f(mm[1]);
        float inv = 1.0f / (amax - amin);
        int n = q >> 2;
        float t = thr[n];
        float4 a = ((const float4*)aggr)[q];
        float4 r;
        r.x = 1.0f / (1.0f + expf(-((a.x - amin) * inv - t)));
        r.y = 1.0f / (1.0f + expf(-((a.y - amin) * inv - t)));
        r.z = 1.0f / (1.0f + expf(-((a.z - amin) * inv - t)));
        r.w = 1.0f / (1.0f + expf(-((a.w - amin) * inv - t)));
        ((float4*)xb)[q] = r;
    }
}

// gather decision nodes + (16x512)@(512x10) matmul, single block of 512 threads
__global__ void final_k(const float* __restrict__ xb, const int* __restrict__ dix,
                        const float* __restrict__ fcw, const float* __restrict__ fcb,
                        float* __restrict__ out) {
    __shared__ float xd[Dd][Bsz];   // 32 KB
    int j = threadIdx.x;
    int n = dix[j];
    #pragma unroll
    for (int b = 0; b < Bsz; b++) xd[j][b] = xb[n * 16 + b];
    __syncthreads();
    if (j < Bsz * Cc) {
        int b = j / Cc, c = j % Cc;
        float acc = fcb[c];
        for (int k = 0; k < Dd; k++) acc += xd[k][b] * fcw[c * Dd + k];
        out[b * Cc + c] = acc;
    }
}

extern "C" void kernel_launch(void* const* d_in, const int* in_sizes, int n_in,
                              void* d_out, int out_size, void* d_ws, size_t ws_size,
                              hipStream_t stream) {
    const float* x    = (const float*)d_in[0];
    const float* ew   = (const float*)d_in[1];
    const float* mult = (const float*)d_in[2];
    const float* nt   = (const float*)d_in[3];
    const float* fcw  = (const float*)d_in[4];
    const float* fcb  = (const float*)d_in[5];
    const int*   ei   = (const int*)d_in[6];
    const int*   dix  = (const int*)d_in[7];
    float* out = (float*)d_out;

    const int* srcv = ei;
    const int* dstv = ei + Ee;

    // workspace layout (~31 MB)
    float* xb      = (float*)d_ws;              // NB
    float* aggr    = xb + NB;                   // NB
    float* thr     = aggr + NB;                 // Nn
    int2*  csr_sw  = (int2*)(thr + Nn);         // Ee (8B aligned)
    uint2* part    = (uint2*)(csr_sw + Ee);     // NPARTS
    int*   row     = (int*)(part + NPARTS);     // Nn+1
    int*   cnt     = row + Nn + 1;              // Nn
    int*   incl    = cnt + Nn;                  // Nn
    int*   bsum    = incl + Nn;                 // NSB
    int*   bofs    = bsum + NSB;                // NSB
    int*   bcur    = bofs + NSB;                // NBK*BPAD
    unsigned* mm   = (unsigned*)(bcur + NBK * BPAD);   // 2

    prep<<<(Nn + 63) / 64, 256, 0, stream>>>(x, nt, xb, thr, cnt);
    hist<<<(Ee + 255) / 256, 256, 0, stream>>>(dstv, cnt);
    scan1<<<NSB, SCAN_BLK, 0, stream>>>(cnt, incl, bsum);
    scan2<<<1, 64, 0, stream>>>(bsum, bofs);
    scan3<<<(Nn + 255) / 256, 256, 0, stream>>>(cnt, incl, bofs, row);
    binit<<<(NBK + 255) / 256, 256, 0, stream>>>(row, bcur);
    bin1<<<(Ee + 255) / 256, 256, 0, stream>>>(srcv, dstv, ew, mult, bcur, csr_sw);
    bin2<<<NBK, 256, 0, stream>>>(row, csr_sw);

    for (int p = 0; p < 4; p++) {
        gather<<<NPARTS, 256, 0, stream>>>(row, csr_sw, xb, aggr, part);
        mm_reduce<<<1, 1024, 0, stream>>>(part, mm);
        update<<<(NB / 4 + 255) / 256, 256, 0, stream>>>(aggr, thr, mm, xb);
    }

    final_k<<<1, 512, 0, stream>>>(xb, dix, fcw, fcb, out);
}

// Round 9
// 368.374 us; speedup vs baseline: 1.3485x; 1.2897x over previous
//
#include <hip/hip_runtime.h>

#define Bsz 16
#define Nn  100000
#define Ee  2000000
#define Dd  512
#define Cc  10
#define NB  (Nn * Bsz)
#define NB4 (NB / 4)                            // 400000 gather threads
#define SCAN_BLK 1024
#define NSB ((Nn + SCAN_BLK - 1) / SCAN_BLK)   // 98
#define NPARTS ((NB4 + 255) / 256)              // 1563 gather blocks
#define NBK 196                                 // dst buckets (512 nodes each)
#define BPAD 16                                 // bucket cursor padding (1/64B line)
#define BE   4096                               // bin1 edges per block
#define SEDMAX 12288                            // bin2 LDS staging cap (96 KB)

// ---- ordered-uint encoding for float min/max (monotone map) ----
__device__ __forceinline__ unsigned enc_f(float f) {
    unsigned u = __float_as_uint(f);
    return (u & 0x80000000u) ? ~u : (u | 0x80000000u);
}
__device__ __forceinline__ float dec_f(unsigned e) {
    unsigned u = (e & 0x80000000u) ? (e ^ 0x80000000u) : ~e;
    return __uint_as_float(u);
}
// f32 -> bf16 RNE (values are finite; no NaN handling needed)
__device__ __forceinline__ unsigned short tob(float f) {
    unsigned u = __float_as_uint(f);
    return (unsigned short)((u + 0x7FFFu + ((u >> 16) & 1u)) >> 16);
}
__device__ __forceinline__ float tof(unsigned short h) {
    return __uint_as_float((unsigned)h << 16);
}

// LDS-tiled transpose x (B,N) -> xh[n*16+b] in bf16 (3.2 MB: per-XCD L2 fits);
// thr[n]=|nt[n]|; zero histogram
__global__ void prep(const float* __restrict__ x, const float* __restrict__ nt,
                     unsigned short* __restrict__ xh, float* __restrict__ thr,
                     int* __restrict__ cnt) {
    __shared__ float sm[16][65];
    int t = threadIdx.x;
    int n0 = blockIdx.x * 64;
    #pragma unroll
    for (int rep = 0; rep < 4; rep++) {
        int r = rep * 4 + (t >> 6);      // batch row 0..15
        int c = t & 63;                  // node within tile
        int n = n0 + c;
        sm[r][c] = (n < Nn) ? x[r * Nn + n] : 0.0f;
    }
    __syncthreads();
    int nn = t >> 2, bq = t & 3;
    int n = n0 + nn;
    if (n < Nn) {
        ushort4 h;
        h.x = tob(sm[bq * 4 + 0][nn]);
        h.y = tob(sm[bq * 4 + 1][nn]);
        h.z = tob(sm[bq * 4 + 2][nn]);
        h.w = tob(sm[bq * 4 + 3][nn]);
        ((ushort4*)xh)[n * 4 + bq] = h;
    }
    int gid = blockIdx.x * 256 + t;
    if (gid < Nn) { thr[gid] = fabsf(nt[gid]); cnt[gid] = 0; }
}

__global__ void hist(const int* __restrict__ dstv, int* __restrict__ cnt) {
    int e = blockIdx.x * blockDim.x + threadIdx.x;
    if (e < Ee) atomicAdd(&cnt[dstv[e]], 1);
}

// per-block inclusive scan (Hillis-Steele) + block sums
__global__ void scan1(const int* __restrict__ cnt, int* __restrict__ incl,
                      int* __restrict__ bsum) {
    __shared__ int s[SCAN_BLK];
    int i = blockIdx.x * SCAN_BLK + threadIdx.x;
    int v = (i < Nn) ? cnt[i] : 0;
    s[threadIdx.x] = v;
    __syncthreads();
    for (int off = 1; off < SCAN_BLK; off <<= 1) {
        int t = (threadIdx.x >= off) ? s[threadIdx.x - off] : 0;
        __syncthreads();
        s[threadIdx.x] += t;
        __syncthreads();
    }
    if (i < Nn) incl[i] = s[threadIdx.x];
    if (threadIdx.x == SCAN_BLK - 1) bsum[blockIdx.x] = s[threadIdx.x];
}

__global__ void scan2(const int* __restrict__ bsum, int* __restrict__ bofs) {
    if (threadIdx.x == 0) {
        int acc = 0;
        for (int k = 0; k < NSB; k++) { bofs[k] = acc; acc += bsum[k]; }
    }
}

// exclusive row offsets
__global__ void scan3(const int* __restrict__ cnt, const int* __restrict__ incl,
                      const int* __restrict__ bofs, int* __restrict__ row) {
    int i = blockIdx.x * blockDim.x + threadIdx.x;
    if (i < Nn) row[i] = incl[i] - cnt[i] + bofs[i / SCAN_BLK];
    if (i == 0) row[Nn] = Ee;
}

// init bucket cursors (one per 64B line)
__global__ void binit(const int* __restrict__ row, int* __restrict__ bcur) {
    int b = blockIdx.x * blockDim.x + threadIdx.x;
    if (b < NBK) bcur[b * BPAD] = row[b * 512];
}

// level-1: LDS-staged bucket partition with BURST writes. Each block stages
// 4096 edges in LDS ordered by bucket, reserves one global range per bucket
// (1 atomic), then copies out: consecutive LDS slots -> consecutive global
// addresses -> full-line coalesced stores (fixes the 7x write amplification
// of per-edge scattered stores, which interleave slots across XCD L2s).
__global__ void bin1(const int* __restrict__ srcv, const int* __restrict__ dstv,
                     const float* __restrict__ ew, const float* __restrict__ mult,
                     int* __restrict__ bcur, int2* __restrict__ csr_sw) {
    __shared__ int2  sdat[BE];       // 32 KB
    __shared__ short sbk[BE];        // 8 KB
    __shared__ int   sbase[NBK];     // local (in-block) exclusive base
    __shared__ int   scur[NBK];      // scatter cursors
    __shared__ int   sg[NBK];        // global base per bucket
    __shared__ int   ss[256];
    int t = threadIdx.x;
    int e0 = blockIdx.x * BE;
    // pass A: histogram (bucket counts for this block's edges)
    if (t < NBK) ss[t] = 0;          // reuse ss as hist accumulator? no: need ss for scan
    __syncthreads();
    // use scur as the histogram first
    if (t < NBK) scur[t] = 0;
    __syncthreads();
    #pragma unroll
    for (int j = 0; j < BE / 256; j++) {
        int e = e0 + t + j * 256;
        if (e < Ee) atomicAdd(&scur[dstv[e] >> 9], 1);
    }
    __syncthreads();
    int v = (t < NBK) ? scur[t] : 0;
    ss[t] = v;
    __syncthreads();
    for (int off = 1; off < 256; off <<= 1) {
        int u = (t >= off) ? ss[t - off] : 0;
        __syncthreads();
        ss[t] += u;
        __syncthreads();
    }
    int excl = ss[t] - v;
    if (t < NBK) {
        if (v > 0) sg[t] = atomicAdd(&bcur[t * BPAD], v);
        sbase[t] = excl;
        scur[t]  = excl;
    }
    __syncthreads();
    // pass B: re-read edges (L2-hot), compute w, scatter into LDS by bucket
    #pragma unroll
    for (int j = 0; j < BE / 256; j++) {
        int e = e0 + t + j * 256;
        if (e < Ee) {
            int d = dstv[e];
            int bk = d >> 9;
            int pos = atomicAdd(&scur[bk], 1);
            int2 p;
            p.x = srcv[e] | ((d & 511) << 17);
            p.y = __float_as_int(ew[e] * tanhf(mult[e]));
            sdat[pos] = p;
            sbk[pos] = (short)bk;
        }
    }
    __syncthreads();
    // pass C: burst copy-out
    int cnt = min(Ee - e0, BE);
    for (int s = t; s < cnt; s += 256) {
        int bk = sbk[s];
        csr_sw[sg[bk] + (s - sbase[bk])] = sdat[s];
    }
}

// level-2: in-place counting sort within each 512-node bucket (LDS staging).
__global__ void bin2(const int* __restrict__ row, int2* __restrict__ csr_sw) {
    __shared__ int2 sed[SEDMAX];     // 96 KB
    __shared__ int lcur[512];
    int b = blockIdx.x;
    int n0 = b * 512;
    int n1 = min(n0 + 512, Nn);
    int e0 = row[n0], e1 = row[n1];
    int cnt = e1 - e0;
    if (cnt > SEDMAX) cnt = SEDMAX;   // statistically unreachable (+20 sigma)
    for (int t = threadIdx.x; t < cnt; t += 256) sed[t] = csr_sw[e0 + t];
    #pragma unroll
    for (int r = 0; r < 2; r++) {
        int nl = r * 256 + threadIdx.x;
        lcur[nl] = (n0 + nl < n1) ? row[n0 + nl] : 0;
    }
    __syncthreads();
    for (int t = threadIdx.x; t < cnt; t += 256) {
        int2 p = sed[t];
        int nl = (p.x >> 17) & 511;
        int pos = atomicAdd(&lcur[nl], 1);
        int2 q;
        q.x = p.x & 0x1FFFF;
        q.y = p.y;
        csr_sw[pos] = q;
    }
}

// thread = (node, b-quad): accumulates float4 from bf16 xh (L2-resident).
// 8-wide edge unroll keeps 8 CSR loads + 8 xh loads in flight.
__global__ void gather(const int* __restrict__ row, const int2* __restrict__ csr_sw,
                       const unsigned short* __restrict__ xh, float* __restrict__ aggr,
                       uint2* __restrict__ part) {
    int i = blockIdx.x * 256 + threadIdx.x;
    bool active = i < NB4;
    float4 acc = make_float4(0.f, 0.f, 0.f, 0.f);
    if (active) {
        int n = i >> 2, bq = i & 3;
        int ks = row[n], ke = row[n + 1];
        const ushort4* x4 = (const ushort4*)xh;
        for (int k = ks; k < ke; k += 8) {
            int2    p[8];
            ushort4 v[8];
            #pragma unroll
            for (int j = 0; j < 8; ++j) {
                int kk = k + j;
                int kc = kk < ke ? kk : ks;          // always a valid index
                p[j] = csr_sw[kc];
                if (kk >= ke) p[j].y = 0;            // 0.0f weight for dead slots
            }
            #pragma unroll
            for (int j = 0; j < 8; ++j) v[j] = x4[p[j].x * 4 + bq];
            #pragma unroll
            for (int j = 0; j < 8; ++j) {
                float w = __int_as_float(p[j].y);
                acc.x += tof(v[j].x) * w;
                acc.y += tof(v[j].y) * w;
                acc.z += tof(v[j].z) * w;
                acc.w += tof(v[j].w) * w;
            }
        }
        ((float4*)aggr)[i] = acc;
    }

    float lmin = active ? fminf(fminf(acc.x, acc.y), fminf(acc.z, acc.w)) : INFINITY;
    float lmax = active ? fmaxf(fmaxf(acc.x, acc.y), fmaxf(acc.z, acc.w)) : -INFINITY;
    #pragma unroll
    for (int off = 32; off > 0; off >>= 1) {
        lmin = fminf(lmin, __shfl_down(lmin, off));
        lmax = fmaxf(lmax, __shfl_down(lmax, off));
    }
    __shared__ float smin[4], smax[4];
    int wid = threadIdx.x >> 6, lane = threadIdx.x & 63;
    if (lane == 0) { smin[wid] = lmin; smax[wid] = lmax; }
    __syncthreads();
    if (threadIdx.x == 0) {
        float m0 = smin[0], M0 = smax[0];
        #pragma unroll
        for (int k = 1; k < 4; k++) { m0 = fminf(m0, smin[k]); M0 = fmaxf(M0, smax[k]); }
        part[blockIdx.x] = make_uint2(enc_f(m0), enc_f(M0));   // plain store
    }
}

// fold per-block partials -> mm[0]=min, mm[1]=max. One block, no atomics.
__global__ void mm_reduce(const uint2* __restrict__ part, unsigned* __restrict__ mm) {
    unsigned lmin = 0xFFFFFFFFu, lmax = 0u;
    for (int i = threadIdx.x; i < NPARTS; i += 1024) {
        uint2 p = part[i];
        lmin = min(lmin, p.x);
        lmax = max(lmax, p.y);
    }
    #pragma unroll
    for (int off = 32; off > 0; off >>= 1) {
        lmin = min(lmin, __shfl_down(lmin, off));
        lmax = max(lmax, __shfl_down(lmax, off));
    }
    __shared__ unsigned smn[16], smx[16];
    int wid = threadIdx.x >> 6, lane = threadIdx.x & 63;
    if (lane == 0) { smn[wid] = lmin; smx[wid] = lmax; }
    __syncthreads();
    if (threadIdx.x == 0) {
        #pragma unroll
        for (int k = 1; k < 16; k++) { lmin = min(lmin, smn[k]); lmax = max(lmax, smx[k]); }
        mm[0] = lmin;
        mm[1] = lmax;
    }
}

// sigmoid update. Passes 0-2: write bf16 xh (gather input). Pass 3: write f32
// result IN-PLACE into aggr (read-then-write same element, safe) for final_k.
__global__ void update(float* __restrict__ aggr, const float* __restrict__ thr,
                       const unsigned* __restrict__ mm, unsigned short* __restrict__ xh,
                       int last) {
    int q = blockIdx.x * blockDim.x + threadIdx.x;   // NB/4 quads
    if (q < NB4) {
        float amin = dec_f(mm[0]), amax = dec_f(mm[1]);
        float inv = 1.0f / (amax - amin);
        int n = q >> 2;
        float t = thr[n];
        float4 a = ((const float4*)aggr)[q];
        float4 r;
        r.x = 1.0f / (1.0f + expf(-((a.x - amin) * inv - t)));
        r.y = 1.0f / (1.0f + expf(-((a.y - amin) * inv - t)));
        r.z = 1.0f / (1.0f + expf(-((a.z - amin) * inv - t)));
        r.w = 1.0f / (1.0f + expf(-((a.w - amin) * inv - t)));
        if (last) {
            ((float4*)aggr)[q] = r;
        } else {
            ushort4 h;
            h.x = tob(r.x); h.y = tob(r.y); h.z = tob(r.z); h.w = tob(r.w);
            ((ushort4*)xh)[q] = h;
        }
    }
}

// gather decision nodes (f32, from aggr) + (16x512)@(512x10) matmul
__global__ void final_k(const float* __restrict__ xf, const int* __restrict__ dix,
                        const float* __restrict__ fcw, const float* __restrict__ fcb,
                        float* __restrict__ out) {
    __shared__ float xd[Dd][Bsz];   // 32 KB
    int j = threadIdx.x;
    int n = dix[j];
    #pragma unroll
    for (int b = 0; b < Bsz; b++) xd[j][b] = xf[n * 16 + b];
    __syncthreads();
    if (j < Bsz * Cc) {
        int b = j / Cc, c = j % Cc;
        float acc = fcb[c];
        for (int k = 0; k < Dd; k++) acc += xd[k][b] * fcw[c * Dd + k];
        out[b * Cc + c] = acc;
    }
}

extern "C" void kernel_launch(void* const* d_in, const int* in_sizes, int n_in,
                              void* d_out, int out_size, void* d_ws, size_t ws_size,
                              hipStream_t stream) {
    const float* x    = (const float*)d_in[0];
    const float* ew   = (const float*)d_in[1];
    const float* mult = (const float*)d_in[2];
    const float* nt   = (const float*)d_in[3];
    const float* fcw  = (const float*)d_in[4];
    const float* fcb  = (const float*)d_in[5];
    const int*   ei   = (const int*)d_in[6];
    const int*   dix  = (const int*)d_in[7];
    float* out = (float*)d_out;

    const int* srcv = ei;
    const int* dstv = ei + Ee;

    // workspace layout (~27 MB)
    unsigned short* xh = (unsigned short*)d_ws;  // NB bf16 (3.2 MB)
    float* aggr    = (float*)(xh + NB);          // NB f32
    float* thr     = aggr + NB;                  // Nn
    int2*  csr_sw  = (int2*)(thr + Nn);          // Ee
    uint2* part    = (uint2*)(csr_sw + Ee);      // NPARTS
    int*   row     = (int*)(part + NPARTS);      // Nn+1
    int*   cnt     = row + Nn + 1;               // Nn
    int*   incl    = cnt + Nn;                   // Nn
    int*   bsum    = incl + Nn;                  // NSB
    int*   bofs    = bsum + NSB;                 // NSB
    int*   bcur    = bofs + NSB;                 // NBK*BPAD
    unsigned* mm   = (unsigned*)(bcur + NBK * BPAD);   // 2

    prep<<<(Nn + 63) / 64, 256, 0, stream>>>(x, nt, xh, thr, cnt);
    hist<<<(Ee + 255) / 256, 256, 0, stream>>>(dstv, cnt);
    scan1<<<NSB, SCAN_BLK, 0, stream>>>(cnt, incl, bsum);
    scan2<<<1, 64, 0, stream>>>(bsum, bofs);
    scan3<<<(Nn + 255) / 256, 256, 0, stream>>>(cnt, incl, bofs, row);
    binit<<<1, 256, 0, stream>>>(row, bcur);
    bin1<<<(Ee + BE - 1) / BE, 256, 0, stream>>>(srcv, dstv, ew, mult, bcur, csr_sw);
    bin2<<<NBK, 256, 0, stream>>>(row, csr_sw);

    for (int p = 0; p < 4; p++) {
        gather<<<NPARTS, 256, 0, stream>>>(row, csr_sw, xh, aggr, part);
        mm_reduce<<<1, 1024, 0, stream>>>(part, mm);
        update<<<(NB4 + 255) / 256, 256, 0, stream>>>(aggr, thr, mm, xh, p == 3);
    }

    final_k<<<1, 512, 0, stream>>>(aggr, dix, fcw, fcb, out);
}

// Round 10
// 292.856 us; speedup vs baseline: 1.6962x; 1.2579x over previous
//
#include <hip/hip_runtime.h>

#define Bsz 16
#define Nn  100000
#define Ee  2000000
#define Dd  512
#define Cc  10
#define NB  (Nn * Bsz)
#define NB4 (NB / 4)                            // 400000 gather threads
#define NPARTS ((NB4 + 255) / 256)              // 1563 gather blocks
#define NBK 196                                 // dst buckets (512 nodes each)
#define BPAD 16                                 // bucket cursor padding (1/64B line)
#define BE   4096                               // bin1/bhist edges per block
#define SEDMAX 12288                            // bin2 LDS staging cap (96 KB)

// ---- ordered-uint encoding for float min/max (monotone map) ----
__device__ __forceinline__ unsigned enc_f(float f) {
    unsigned u = __float_as_uint(f);
    return (u & 0x80000000u) ? ~u : (u | 0x80000000u);
}
__device__ __forceinline__ float dec_f(unsigned e) {
    unsigned u = (e & 0x80000000u) ? (e ^ 0x80000000u) : ~e;
    return __uint_as_float(u);
}
// f32 -> bf16 RNE (values are finite; no NaN handling needed)
__device__ __forceinline__ unsigned short tob(float f) {
    unsigned u = __float_as_uint(f);
    return (unsigned short)((u + 0x7FFFu + ((u >> 16) & 1u)) >> 16);
}
__device__ __forceinline__ float tof(unsigned short h) {
    return __uint_as_float((unsigned)h << 16);
}

// LDS-tiled transpose x (B,N) -> xh[n*16+b] in bf16 (3.2 MB: per-XCD L2 fits);
// thr[n]=|nt[n]|; zero bucket counts
__global__ void prep(const float* __restrict__ x, const float* __restrict__ nt,
                     unsigned short* __restrict__ xh, float* __restrict__ thr,
                     int* __restrict__ bcnt) {
    __shared__ float sm[16][65];
    int t = threadIdx.x;
    int n0 = blockIdx.x * 64;
    #pragma unroll
    for (int rep = 0; rep < 4; rep++) {
        int r = rep * 4 + (t >> 6);      // batch row 0..15
        int c = t & 63;                  // node within tile
        int n = n0 + c;
        sm[r][c] = (n < Nn) ? x[r * Nn + n] : 0.0f;
    }
    __syncthreads();
    int nn = t >> 2, bq = t & 3;
    int n = n0 + nn;
    if (n < Nn) {
        ushort4 h;
        h.x = tob(sm[bq * 4 + 0][nn]);
        h.y = tob(sm[bq * 4 + 1][nn]);
        h.z = tob(sm[bq * 4 + 2][nn]);
        h.w = tob(sm[bq * 4 + 3][nn]);
        ((ushort4*)xh)[n * 4 + bq] = h;
    }
    int gid = blockIdx.x * 256 + t;
    if (gid < Nn) thr[gid] = fabsf(nt[gid]);
    if (gid < NBK) bcnt[gid] = 0;
}

// bucket-level histogram: LDS accumulation, <=196 global atomics per block
// (96K total vs 2M per-node atomics, whose memory-side RMWs cost ~32B HBM
// traffic each -- the round-9 top kernel at 81us/62MB)
__global__ void bhist(const int* __restrict__ dstv, int* __restrict__ bcnt) {
    __shared__ int lh[NBK];
    int t = threadIdx.x;
    if (t < NBK) lh[t] = 0;
    __syncthreads();
    int e = blockIdx.x * BE + t;
    #pragma unroll
    for (int j = 0; j < BE / 256; j++, e += 256)
        if (e < Ee) atomicAdd(&lh[dstv[e] >> 9], 1);
    __syncthreads();
    if (t < NBK && lh[t] > 0) atomicAdd(&bcnt[t], lh[t]);
}

// scan 196 bucket counts -> bucket bases + cursors (single block)
__global__ void bscan(const int* __restrict__ bcnt, int* __restrict__ bbase,
                      int* __restrict__ bcur) {
    __shared__ int s[256];
    int t = threadIdx.x;
    int v = (t < NBK) ? bcnt[t] : 0;
    s[t] = v;
    __syncthreads();
    for (int off = 1; off < 256; off <<= 1) {
        int u = (t >= off) ? s[t - off] : 0;
        __syncthreads();
        s[t] += u;
        __syncthreads();
    }
    if (t < NBK) {
        int excl = s[t] - v;
        bbase[t] = excl;
        bcur[t * BPAD] = excl;
    }
    if (t == 0) bbase[NBK] = Ee;
}

// level-1: LDS-staged bucket partition with BURST writes. Each block stages
// 4096 edges in LDS ordered by bucket, reserves one global range per bucket
// (1 atomic), then copies out: consecutive LDS slots -> consecutive global
// addresses -> full-line coalesced stores.
__global__ void bin1(const int* __restrict__ srcv, const int* __restrict__ dstv,
                     const float* __restrict__ ew, const float* __restrict__ mult,
                     int* __restrict__ bcur, int2* __restrict__ csr_sw) {
    __shared__ int2  sdat[BE];       // 32 KB
    __shared__ short sbk[BE];        // 8 KB
    __shared__ int   sbase[NBK];     // local (in-block) exclusive base
    __shared__ int   scur[NBK];      // histogram, then scatter cursors
    __shared__ int   sg[NBK];        // global base per bucket
    __shared__ int   ss[256];
    int t = threadIdx.x;
    int e0 = blockIdx.x * BE;
    if (t < NBK) scur[t] = 0;
    __syncthreads();
    // pass A: block-local bucket histogram
    #pragma unroll
    for (int j = 0; j < BE / 256; j++) {
        int e = e0 + t + j * 256;
        if (e < Ee) atomicAdd(&scur[dstv[e] >> 9], 1);
    }
    __syncthreads();
    int v = (t < NBK) ? scur[t] : 0;
    ss[t] = v;
    __syncthreads();
    for (int off = 1; off < 256; off <<= 1) {
        int u = (t >= off) ? ss[t - off] : 0;
        __syncthreads();
        ss[t] += u;
        __syncthreads();
    }
    int excl = ss[t] - v;
    if (t < NBK) {
        if (v > 0) sg[t] = atomicAdd(&bcur[t * BPAD], v);
        sbase[t] = excl;
        scur[t]  = excl;
    }
    __syncthreads();
    // pass B: re-read edges (L2-hot), compute w, scatter into LDS by bucket
    #pragma unroll
    for (int j = 0; j < BE / 256; j++) {
        int e = e0 + t + j * 256;
        if (e < Ee) {
            int d = dstv[e];
            int bk = d >> 9;
            int pos = atomicAdd(&scur[bk], 1);
            int2 p;
            p.x = srcv[e] | ((d & 511) << 17);
            p.y = __float_as_int(ew[e] * tanhf(mult[e]));
            sdat[pos] = p;
            sbk[pos] = (short)bk;
        }
    }
    __syncthreads();
    // pass C: burst copy-out
    int cnt = min(Ee - e0, BE);
    for (int s = t; s < cnt; s += 256) {
        int bk = sbk[s];
        csr_sw[sg[bk] + (s - sbase[bk])] = sdat[s];
    }
}

// level-2: per 512-node bucket: stage edges in LDS, build per-node histogram
// + scan IN LDS (no global per-node atomics anywhere), write row[] coalesced,
// counting-sort in place.
__global__ __launch_bounds__(512) void bin2(const int* __restrict__ bbase,
                                            int2* __restrict__ csr_sw,
                                            int* __restrict__ row) {
    __shared__ int2 sed[SEDMAX];     // 96 KB
    __shared__ int  lh[512];         // hist -> cursors
    __shared__ int  lscan[512];
    int b = blockIdx.x;
    int n0 = b * 512;
    int n1 = min(n0 + 512, Nn);
    int e0 = bbase[b], e1 = bbase[b + 1];
    int cnt = e1 - e0;
    if (cnt > SEDMAX) cnt = SEDMAX;   // statistically unreachable (+20 sigma)
    int t = threadIdx.x;
    lh[t] = 0;
    for (int s = t; s < cnt; s += 512) sed[s] = csr_sw[e0 + s];
    __syncthreads();
    for (int s = t; s < cnt; s += 512) atomicAdd(&lh[(sed[s].x >> 17) & 511], 1);
    __syncthreads();
    int v = lh[t];
    lscan[t] = v;
    __syncthreads();
    for (int off = 1; off < 512; off <<= 1) {
        int u = (t >= off) ? lscan[t - off] : 0;
        __syncthreads();
        lscan[t] += u;
        __syncthreads();
    }
    int excl = lscan[t] - v;
    int n = n0 + t;
    if (n < n1) row[n] = e0 + excl;
    if (b == NBK - 1 && t == 0) row[Nn] = Ee;
    lh[t] = excl;                    // local cursors
    __syncthreads();
    for (int s = t; s < cnt; s += 512) {
        int2 p = sed[s];
        int nl = (p.x >> 17) & 511;
        int pos = atomicAdd(&lh[nl], 1);
        csr_sw[e0 + pos] = make_int2(p.x & 0x1FFFF, p.y);
    }
}

// thread = (node, b-quad): accumulates float4 from bf16 xh (L2-resident).
// 8-wide edge unroll keeps 8 CSR loads + 8 xh loads in flight.
__global__ void gather(const int* __restrict__ row, const int2* __restrict__ csr_sw,
                       const unsigned short* __restrict__ xh, float* __restrict__ aggr,
                       uint2* __restrict__ part) {
    int i = blockIdx.x * 256 + threadIdx.x;
    bool active = i < NB4;
    float4 acc = make_float4(0.f, 0.f, 0.f, 0.f);
    if (active) {
        int n = i >> 2, bq = i & 3;
        int ks = row[n], ke = row[n + 1];
        const ushort4* x4 = (const ushort4*)xh;
        for (int k = ks; k < ke; k += 8) {
            int2    p[8];
            ushort4 v[8];
            #pragma unroll
            for (int j = 0; j < 8; ++j) {
                int kk = k + j;
                int kc = kk < ke ? kk : ks;          // always a valid index
                p[j] = csr_sw[kc];
                if (kk >= ke) p[j].y = 0;            // 0.0f weight for dead slots
            }
            #pragma unroll
            for (int j = 0; j < 8; ++j) v[j] = x4[p[j].x * 4 + bq];
            #pragma unroll
            for (int j = 0; j < 8; ++j) {
                float w = __int_as_float(p[j].y);
                acc.x += tof(v[j].x) * w;
                acc.y += tof(v[j].y) * w;
                acc.z += tof(v[j].z) * w;
                acc.w += tof(v[j].w) * w;
            }
        }
        ((float4*)aggr)[i] = acc;
    }

    float lmin = active ? fminf(fminf(acc.x, acc.y), fminf(acc.z, acc.w)) : INFINITY;
    float lmax = active ? fmaxf(fmaxf(acc.x, acc.y), fmaxf(acc.z, acc.w)) : -INFINITY;
    #pragma unroll
    for (int off = 32; off > 0; off >>= 1) {
        lmin = fminf(lmin, __shfl_down(lmin, off));
        lmax = fmaxf(lmax, __shfl_down(lmax, off));
    }
    __shared__ float smin[4], smax[4];
    int wid = threadIdx.x >> 6, lane = threadIdx.x & 63;
    if (lane == 0) { smin[wid] = lmin; smax[wid] = lmax; }
    __syncthreads();
    if (threadIdx.x == 0) {
        float m0 = smin[0], M0 = smax[0];
        #pragma unroll
        for (int k = 1; k < 4; k++) { m0 = fminf(m0, smin[k]); M0 = fmaxf(M0, smax[k]); }
        part[blockIdx.x] = make_uint2(enc_f(m0), enc_f(M0));   // plain store
    }
}

// fold per-block partials -> mm[0]=min, mm[1]=max. One block, no atomics.
__global__ void mm_reduce(const uint2* __restrict__ part, unsigned* __restrict__ mm) {
    unsigned lmin = 0xFFFFFFFFu, lmax = 0u;
    for (int i = threadIdx.x; i < NPARTS; i += 1024) {
        uint2 p = part[i];
        lmin = min(lmin, p.x);
        lmax = max(lmax, p.y);
    }
    #pragma unroll
    for (int off = 32; off > 0; off >>= 1) {
        lmin = min(lmin, __shfl_down(lmin, off));
        lmax = max(lmax, __shfl_down(lmax, off));
    }
    __shared__ unsigned smn[16], smx[16];
    int wid = threadIdx.x >> 6, lane = threadIdx.x & 63;
    if (lane == 0) { smn[wid] = lmin; smx[wid] = lmax; }
    __syncthreads();
    if (threadIdx.x == 0) {
        #pragma unroll
        for (int k = 1; k < 16; k++) { lmin = min(lmin, smn[k]); lmax = max(lmax, smx[k]); }
        mm[0] = lmin;
        mm[1] = lmax;
    }
}

// sigmoid update. Passes 0-2: write bf16 xh (gather input). Pass 3: write f32
// result IN-PLACE into aggr (read-then-write same element, safe) for final_k.
__global__ void update(float* __restrict__ aggr, const float* __restrict__ thr,
                       const unsigned* __restrict__ mm, unsigned short* __restrict__ xh,
                       int last) {
    int q = blockIdx.x * blockDim.x + threadIdx.x;   // NB/4 quads
    if (q < NB4) {
        float amin = dec_f(mm[0]), amax = dec_f(mm[1]);
        float inv = 1.0f / (amax - amin);
        int n = q >> 2;
        float t = thr[n];
        float4 a = ((const float4*)aggr)[q];
        float4 r;
        r.x = 1.0f / (1.0f + expf(-((a.x - amin) * inv - t)));
        r.y = 1.0f / (1.0f + expf(-((a.y - amin) * inv - t)));
        r.z = 1.0f / (1.0f + expf(-((a.z - amin) * inv - t)));
        r.w = 1.0f / (1.0f + expf(-((a.w - amin) * inv - t)));
        if (last) {
            ((float4*)aggr)[q] = r;
        } else {
            ushort4 h;
            h.x = tob(r.x); h.y = tob(r.y); h.z = tob(r.z); h.w = tob(r.w);
            ((ushort4*)xh)[q] = h;
        }
    }
}

// gather decision nodes (f32, from aggr) + (16x512)@(512x10) matmul
__global__ void final_k(const float* __restrict__ xf, const int* __restrict__ dix,
                        const float* __restrict__ fcw, const float* __restrict__ fcb,
                        float* __restrict__ out) {
    __shared__ float xd[Dd][Bsz];   // 32 KB
    int j = threadIdx.x;
    int n = dix[j];
    #pragma unroll
    for (int b = 0; b < Bsz; b++) xd[j][b] = xf[n * 16 + b];
    __syncthreads();
    if (j < Bsz * Cc) {
        int b = j / Cc, c = j % Cc;
        float acc = fcb[c];
        for (int k = 0; k < Dd; k++) acc += xd[k][b] * fcw[c * Dd + k];
        out[b * Cc + c] = acc;
    }
}

extern "C" void kernel_launch(void* const* d_in, const int* in_sizes, int n_in,
                              void* d_out, int out_size, void* d_ws, size_t ws_size,
                              hipStream_t stream) {
    const float* x    = (const float*)d_in[0];
    const float* ew   = (const float*)d_in[1];
    const float* mult = (const float*)d_in[2];
    const float* nt   = (const float*)d_in[3];
    const float* fcw  = (const float*)d_in[4];
    const float* fcb  = (const float*)d_in[5];
    const int*   ei   = (const int*)d_in[6];
    const int*   dix  = (const int*)d_in[7];
    float* out = (float*)d_out;

    const int* srcv = ei;
    const int* dstv = ei + Ee;

    // workspace layout (~26 MB)
    unsigned short* xh = (unsigned short*)d_ws;  // NB bf16 (3.2 MB)
    float* aggr    = (float*)(xh + NB);          // NB f32
    float* thr     = aggr + NB;                  // Nn
    int2*  csr_sw  = (int2*)(thr + Nn);          // Ee
    uint2* part    = (uint2*)(csr_sw + Ee);      // NPARTS
    int*   row     = (int*)(part + NPARTS);      // Nn+1
    int*   bcnt    = row + Nn + 1;               // NBK
    int*   bbase   = bcnt + NBK;                 // NBK+1
    int*   bcur    = bbase + NBK + 1;            // NBK*BPAD
    unsigned* mm   = (unsigned*)(bcur + NBK * BPAD);   // 2

    prep<<<(Nn + 63) / 64, 256, 0, stream>>>(x, nt, xh, thr, bcnt);
    bhist<<<(Ee + BE - 1) / BE, 256, 0, stream>>>(dstv, bcnt);
    bscan<<<1, 256, 0, stream>>>(bcnt, bbase, bcur);
    bin1<<<(Ee + BE - 1) / BE, 256, 0, stream>>>(srcv, dstv, ew, mult, bcur, csr_sw);
    bin2<<<NBK, 512, 0, stream>>>(bbase, csr_sw, row);

    for (int p = 0; p < 4; p++) {
        gather<<<NPARTS, 256, 0, stream>>>(row, csr_sw, xh, aggr, part);
        mm_reduce<<<1, 1024, 0, stream>>>(part, mm);
        update<<<(NB4 + 255) / 256, 256, 0, stream>>>(aggr, thr, mm, xh, p == 3);
    }

    final_k<<<1, 512, 0, stream>>>(aggr, dix, fcw, fcb, out);
}